// Round 1
// baseline (499.955 us; speedup 1.0000x reference)
//
#include <hip/hip_runtime.h>
#include <hip/hip_bf16.h>
#include <hip/hip_fp16.h>

// ---------------- problem constants ----------------
#define BATCH 256
#define NEXP 200000
#define DS 96
#define DA 32
#define DIM 128
#define NCHUNK 64                 // atoms per k_dist block
#define NBLK (NEXP / NCHUNK)      // 3125
#define ESTRIDE 136               // padded LDS row stride (shorts) -> stride%32words==4
#define CAND_MAX 1024
#define COUNT_TARGET 240          // need ~199.8 atoms; margin for approx-vs-exact rank noise
#define BIN_N 1024
#define BIN_SCALE 8.0f            // bin = floor(d * 8): 0.125 resolution, covers d < 128

static __device__ __forceinline__ float target_w() { return (float)(1.0 / 1000.0 - 1e-6); }
#define RBW 441.94173824159216    // 5.0*1000/sqrt(128)

typedef short short8v __attribute__((ext_vector_type(8)));
typedef float f32x4 __attribute__((ext_vector_type(4)));

// ws layout (bytes)
#define OFF_D2   0                        // fp16 [BATCH][NEXP]  = 102,400,000
#define OFF_ABF  102400000                // ushort[BATCH*DIM]   = 65,536
#define OFF_AF32 102465536                // float [BATCH*DIM]   = 131,072
#define OFF_A2   102596608                // float [BATCH]       = 1,024
#define WS_NEEDED 102597632

__device__ __forceinline__ unsigned short f2bf(float x) {
    __hip_bfloat16 h = __float2bfloat16(x);
    return __builtin_bit_cast(unsigned short, h);
}

// ---------------- K1: agent prep ----------------
__global__ __launch_bounds__(128) void k_agent(const float* __restrict__ state,
                                               const float* __restrict__ action,
                                               const float* __restrict__ mean,
                                               const float* __restrict__ stdv,
                                               float* __restrict__ agent_f32,
                                               unsigned short* __restrict__ agent_bf16,
                                               float* __restrict__ a2) {
    int b = blockIdx.x, d = threadIdx.x;
    float v = (d < DS) ? state[b * DS + d] : action[b * DA + (d - DS)];
    float nrm = (v - mean[d]) / stdv[d];
    agent_f32[b * DIM + d] = nrm;
    agent_bf16[b * DIM + d] = f2bf(nrm);
    __shared__ float red[128];
    red[d] = nrm * nrm;
    __syncthreads();
    for (int s = 64; s > 0; s >>= 1) {
        if (d < s) red[d] += red[d + s];
        __syncthreads();
    }
    if (d == 0) a2[b] = red[0];
}

// ---------------- K2: bf16 MFMA distances -> fp16 d2 ----------------
// Block: 256 threads (4 waves). Tile: all 256 rows x 64 atoms. mfma_f32_16x16x32_bf16.
// A-frag layout: A[m=lane&15][k=quad*8+j]; B-frag: B[n=lane&15][k=quad*8+j];
// C/D: col(n)=lane&15, row(m)=quad*4+reg   [guide §3, m89/m91-verified]
__global__ __launch_bounds__(256) void k_dist(const float* __restrict__ experts,
                                              const float* __restrict__ mean,
                                              const float* __restrict__ stdv,
                                              const unsigned short* __restrict__ agent_bf16,
                                              const float* __restrict__ a2,
                                              _Float16* __restrict__ d2ws) {
    __shared__ unsigned short elds[NCHUNK * ESTRIDE];
    __shared__ float e2l[NCHUNK];
    __shared__ float meanl[DIM], rstdl[DIM];

    int t = threadIdx.x;
    int chunk = blockIdx.x;
    int lane = t & 63, wave = t >> 6, quad = lane >> 4, lm = lane & 15;

    if (t < DIM) { meanl[t] = mean[t]; rstdl[t] = 1.0f / stdv[t]; }
    if (t < NCHUNK) e2l[t] = 0.f;
    __syncthreads();

    // A fragments in registers: rows wave*64 + mt*16 + lm
    short8v afrag[4][4];
#pragma unroll
    for (int mt = 0; mt < 4; ++mt)
#pragma unroll
        for (int kk = 0; kk < 4; ++kk) {
            int row = wave * 64 + mt * 16 + lm;
            const uint4* p = reinterpret_cast<const uint4*>(agent_bf16 + row * DIM + kk * 32 + quad * 8);
            afrag[mt][kk] = __builtin_bit_cast(short8v, *p);
        }

    // stage expert chunk: normalize fp32 -> bf16 LDS, accumulate e2
    const float4* e4 = reinterpret_cast<const float4*>(experts) + (size_t)chunk * (NCHUNK * DIM / 4);
#pragma unroll
    for (int j = 0; j < 8; ++j) {
        int i4 = t + 256 * j;                 // < 2048
        float4 v = e4[i4];
        int dbase = (i4 & 31) * 4;
        int atom = i4 >> 5;
        float n0 = (v.x - meanl[dbase + 0]) * rstdl[dbase + 0];
        float n1 = (v.y - meanl[dbase + 1]) * rstdl[dbase + 1];
        float n2 = (v.z - meanl[dbase + 2]) * rstdl[dbase + 2];
        float n3 = (v.w - meanl[dbase + 3]) * rstdl[dbase + 3];
        atomicAdd(&e2l[atom], n0 * n0 + n1 * n1 + n2 * n2 + n3 * n3);
        ushort4 h;
        h.x = f2bf(n0); h.y = f2bf(n1); h.z = f2bf(n2); h.w = f2bf(n3);
        *reinterpret_cast<ushort4*>(&elds[atom * ESTRIDE + dbase]) = h;
    }
    __syncthreads();

    f32x4 zero4 = {0.f, 0.f, 0.f, 0.f};
    f32x4 acc[4][4];
#pragma unroll
    for (int mt = 0; mt < 4; ++mt)
#pragma unroll
        for (int nt = 0; nt < 4; ++nt) acc[mt][nt] = zero4;

#pragma unroll
    for (int kk = 0; kk < 4; ++kk) {
        short8v bfrag[4];
#pragma unroll
        for (int nt = 0; nt < 4; ++nt) {
            const uint4* p = reinterpret_cast<const uint4*>(&elds[(nt * 16 + lm) * ESTRIDE + kk * 32 + quad * 8]);
            bfrag[nt] = __builtin_bit_cast(short8v, *p);
        }
#pragma unroll
        for (int mt = 0; mt < 4; ++mt)
#pragma unroll
            for (int nt = 0; nt < 4; ++nt)
                acc[mt][nt] = __builtin_amdgcn_mfma_f32_16x16x32_bf16(afrag[mt][kk], bfrag[nt], acc[mt][nt], 0, 0, 0);
    }

    // epilogue: d2 = a2 + e2 - 2*dot -> fp16
#pragma unroll
    for (int mt = 0; mt < 4; ++mt) {
#pragma unroll
        for (int nt = 0; nt < 4; ++nt) {
            int atoml = nt * 16 + lm;
            float e2v = e2l[atoml];
#pragma unroll
            for (int r = 0; r < 4; ++r) {
                int row = wave * 64 + mt * 16 + quad * 4 + r;
                float d2 = a2[row] + e2v - 2.0f * acc[mt][nt][r];
                d2ws[(size_t)row * NEXP + chunk * NCHUNK + atoml] = (_Float16)d2;
            }
        }
    }
}

// ---------------- K3: per-row select + exact refine + greedy ----------------
__global__ __launch_bounds__(256) void k_select(const _Float16* __restrict__ d2ws,
                                                const float* __restrict__ experts,
                                                const float* __restrict__ weights,
                                                const float* __restrict__ mean,
                                                const float* __restrict__ stdv,
                                                const float* __restrict__ agent_f32,
                                                float* __restrict__ out) {
    __shared__ unsigned int hist[BIN_N];
    __shared__ float meanl[DIM], rstdl[DIM], agl[DIM];
    __shared__ int cidx[CAND_MAX];
    __shared__ float cd2[CAND_MAX];
    __shared__ float cw[CAND_MAX];
    __shared__ float psA[CAND_MAX], psB[CAND_MAX];
    __shared__ int cntS, tauS;
    __shared__ float red[256];

    int t = threadIdx.x;
    int row = blockIdx.x;
    for (int i = t; i < BIN_N; i += 256) hist[i] = 0;
    if (t < DIM) {
        meanl[t] = mean[t];
        rstdl[t] = 1.0f / stdv[t];
        agl[t] = agent_f32[row * DIM + t];
    }
    if (t == 0) cntS = 0;
    __syncthreads();

    const uint4* r4 = reinterpret_cast<const uint4*>(d2ws + (size_t)row * NEXP);  // 25000 uint4

    // pass A: histogram on approx d
    for (int it = 0; it < 98; ++it) {
        int i4 = t + 256 * it;
        if (i4 < 25000) {
            uint4 v = r4[i4];
            unsigned int wv[4] = {v.x, v.y, v.z, v.w};
#pragma unroll
            for (int q = 0; q < 4; ++q)
#pragma unroll
                for (int hh = 0; hh < 2; ++hh) {
                    unsigned short bits = (unsigned short)((wv[q] >> (16 * hh)) & 0xffffu);
                    float d2f = (float)__builtin_bit_cast(_Float16, bits);
                    int bn = (int)(sqrtf(fmaxf(d2f, 0.f)) * BIN_SCALE);
                    bn = bn < 0 ? 0 : (bn > BIN_N - 1 ? BIN_N - 1 : bn);
                    atomicAdd(&hist[bn], 1u);
                }
        }
    }
    __syncthreads();
    if (t == 0) {
        unsigned int cum = 0;
        int T = BIN_N - 1;
        for (int i = 0; i < BIN_N; ++i) {
            cum += hist[i];
            if (cum >= COUNT_TARGET) { T = i; break; }
        }
        int tau = T;
        unsigned int c = cum;
        for (int e = 1; e <= 2; ++e) {
            if (T + e >= BIN_N) break;
            c += hist[T + e];
            if (c <= CAND_MAX) tau = T + e;
            else break;
        }
        tauS = tau;
    }
    __syncthreads();
    int tau = tauS;

    // pass B: compact candidate indices (L2/L3-warm re-read)
    for (int it = 0; it < 98; ++it) {
        int i4 = t + 256 * it;
        if (i4 < 25000) {
            uint4 v = r4[i4];
            unsigned int wv[4] = {v.x, v.y, v.z, v.w};
#pragma unroll
            for (int q = 0; q < 4; ++q)
#pragma unroll
                for (int hh = 0; hh < 2; ++hh) {
                    unsigned short bits = (unsigned short)((wv[q] >> (16 * hh)) & 0xffffu);
                    float d2f = (float)__builtin_bit_cast(_Float16, bits);
                    int bn = (int)(sqrtf(fmaxf(d2f, 0.f)) * BIN_SCALE);
                    bn = bn < 0 ? 0 : (bn > BIN_N - 1 ? BIN_N - 1 : bn);
                    if (bn <= tau) {
                        int pos = atomicAdd(&cntS, 1);
                        if (pos < CAND_MAX) cidx[pos] = i4 * 8 + q * 2 + hh;
                    }
                }
        }
    }
    __syncthreads();
    int nc = min(cntS, CAND_MAX);

    // refine: exact fp32 d2, 16 lanes per candidate (coalesced 512B gathers)
    int g = t >> 4, p = t & 15;
    for (int c = g; c < CAND_MAX; c += 16) {
        if (c < nc) {
            int idx = cidx[c];
            const float4* ep = reinterpret_cast<const float4*>(experts + (size_t)idx * DIM);
            float4 e0 = ep[p * 2], e1 = ep[p * 2 + 1];
            int d0 = p * 8;
            float s = 0.f, x;
            x = (e0.x - meanl[d0 + 0]) * rstdl[d0 + 0] - agl[d0 + 0]; s += x * x;
            x = (e0.y - meanl[d0 + 1]) * rstdl[d0 + 1] - agl[d0 + 1]; s += x * x;
            x = (e0.z - meanl[d0 + 2]) * rstdl[d0 + 2] - agl[d0 + 2]; s += x * x;
            x = (e0.w - meanl[d0 + 3]) * rstdl[d0 + 3] - agl[d0 + 3]; s += x * x;
            x = (e1.x - meanl[d0 + 4]) * rstdl[d0 + 4] - agl[d0 + 4]; s += x * x;
            x = (e1.y - meanl[d0 + 5]) * rstdl[d0 + 5] - agl[d0 + 5]; s += x * x;
            x = (e1.z - meanl[d0 + 6]) * rstdl[d0 + 6] - agl[d0 + 6]; s += x * x;
            x = (e1.w - meanl[d0 + 7]) * rstdl[d0 + 7] - agl[d0 + 7]; s += x * x;
#pragma unroll
            for (int o = 8; o >= 1; o >>= 1) s += __shfl_xor(s, o, 64);
            if (p == 0) { cd2[c] = s; cw[c] = weights[idx]; }
        } else if (p == 0) {
            cd2[c] = 3.0e38f; cw[c] = 0.f; cidx[c] = 0x7fffffff;
        }
    }
    __syncthreads();

    // bitonic sort ascending by (d2, idx) — mimics stable argsort
    for (int k = 2; k <= CAND_MAX; k <<= 1) {
        for (int j = k >> 1; j > 0; j >>= 1) {
            for (int i = t; i < CAND_MAX; i += 256) {
                int ixj = i ^ j;
                if (ixj > i) {
                    bool up = ((i & k) == 0);
                    float da = cd2[i], db = cd2[ixj];
                    int ia = cidx[i], ib = cidx[ixj];
                    bool gtr = (da > db) || (da == db && ia > ib);
                    if (gtr == up) {
                        cd2[i] = db; cd2[ixj] = da;
                        cidx[i] = ib; cidx[ixj] = ia;
                        float wa = cw[i]; cw[i] = cw[ixj]; cw[ixj] = wa;
                    }
                }
            }
            __syncthreads();
        }
    }

    // inclusive prefix sum of weights (Hillis-Steele)
    for (int i = t; i < CAND_MAX; i += 256) psA[i] = cw[i];
    __syncthreads();
    float* src = psA;
    float* dst = psB;
    for (int off = 1; off < CAND_MAX; off <<= 1) {
        for (int i = t; i < CAND_MAX; i += 256)
            dst[i] = src[i] + (i >= off ? src[i - off] : 0.f);
        __syncthreads();
        float* tmp = src; src = dst; dst = tmp;
    }

    // greedy consume: take = clip(TARGET - cum_prev, 0, w); cost = sum take*d
    float TGT = target_w();
    float partial = 0.f;
    for (int i = t; i < CAND_MAX; i += 256) {
        float w = cw[i];
        float cumprev = src[i] - w;
        float take = fminf(fmaxf(TGT - cumprev, 0.f), w);
        if (take > 0.f) partial += take * sqrtf(fmaxf(cd2[i], 1e-12f));
    }
    red[t] = partial;
    __syncthreads();
    for (int s = 128; s > 0; s >>= 1) {
        if (t < s) red[t] += red[t + s];
        __syncthreads();
    }
    if (t == 0) out[row] = 5.0f * expf(-(float)RBW * red[0]);
}

// ---------------- launch ----------------
extern "C" void kernel_launch(void* const* d_in, const int* in_sizes, int n_in,
                              void* d_out, int out_size, void* d_ws, size_t ws_size,
                              hipStream_t stream) {
    const float* state   = (const float*)d_in[0];
    const float* action  = (const float*)d_in[1];
    const float* experts = (const float*)d_in[2];
    const float* weights = (const float*)d_in[3];
    const float* mean    = (const float*)d_in[4];
    const float* stdv    = (const float*)d_in[5];
    float* out = (float*)d_out;

    if (ws_size < (size_t)WS_NEEDED) return;  // ws too small: fail cleanly (wrong answer, no OOB)

    char* ws = (char*)d_ws;
    _Float16* d2ws            = (_Float16*)(ws + OFF_D2);
    unsigned short* agent_bf16 = (unsigned short*)(ws + OFF_ABF);
    float* agent_f32          = (float*)(ws + OFF_AF32);
    float* a2                 = (float*)(ws + OFF_A2);

    k_agent<<<BATCH, 128, 0, stream>>>(state, action, mean, stdv, agent_f32, agent_bf16, a2);
    k_dist<<<NBLK, 256, 0, stream>>>(experts, mean, stdv, agent_bf16, a2, d2ws);
    k_select<<<BATCH, 256, 0, stream>>>(d2ws, experts, weights, mean, stdv, agent_f32, out);
}